// Round 10
// baseline (620.316 us; speedup 1.0000x reference)
//
#include <hip/hip_runtime.h>
#include <hip/hip_bf16.h>

typedef __attribute__((ext_vector_type(8))) short short8;
typedef __attribute__((ext_vector_type(4))) short short4_t;
typedef __attribute__((ext_vector_type(4))) float floatx4;
typedef __attribute__((ext_vector_type(16))) float floatx16;

#define MFMA_B16(a,b,c) __builtin_amdgcn_mfma_f32_16x16x32_bf16((a),(b),(c),0,0,0)
#define MFMA32(a,b,c)   __builtin_amdgcn_mfma_f32_32x32x16_bf16((a),(b),(c),0,0,0)

__device__ __forceinline__ short f2bf(float f) {
    union { __hip_bfloat16 h; short s; } u;
    u.h = __float2bfloat16(f);
    return u.s;
}

union S8U { short4_t h[2]; short8 v; };

// ---------------- problem constants ----------------
#define N_FRAMES 4096
#define C_IN     9
#define POS      121
#define NF       64
#define FC_K     7744     // k = p*64 + c
#define ISTR     20       // conv0 input LDS stride (elems)
#define FSZ      10816    // 169*64 elems per frame LDS image

// ---------------- workspace offsets (bytes) ----------------
#define OFF_W0    0                       // [9][2][32][16] bf16 (18432 B)
#define OFF_WP    18432                   // [7][9][2][4][32][2][8] bf16 (516096 B)
#define OFF_FCP   534528                  // [64][7744] bf16, k=p*64+c (991232 B)
#define OFF_WIHT  1525760                 // [64][256] f32 (65536 B)
#define OFF_BSUM  1591296                 // [256] f32 (1024 B)
#define OFF_ACTS  1592320                 // [4096][7744] bf16 (63438848 B)
#define OFF_XG    66079744                // [4096][256] f32 (4194304 B)
#define OFF_HOUT  70274048                // [4096][64] f32 (1048576 B)  end=71322624

// ============ fused prep: conv weights + w_ih^T + biases + fc transpose ============
__global__ __launch_bounds__(256) void prep_kernel(
    const float* __restrict__ conv0_w, const float* __restrict__ conv_ws,
    const float* __restrict__ w_ih,
    const float* __restrict__ b_ih, const float* __restrict__ b_hh,
    const float* __restrict__ fc_w,
    short* __restrict__ w0, short* __restrict__ wpk,
    float* __restrict__ wihT, float* __restrict__ bsum,
    short* __restrict__ fcp)
{
    __shared__ float row[FC_K];          // 30976 B (used by fc-transpose blocks)
    const int tid = threadIdx.x;
    if (blockIdx.x < 64) {               // fc weight transpose: [u][c*121+p] -> [u][p*64+c]
        const int u = blockIdx.x;
        const float* src = fc_w + (size_t)u*FC_K;
        for (int i = tid; i < FC_K; i += 256) row[i] = src[i];
        __syncthreads();
        short* dst = fcp + (size_t)u*FC_K;
        for (int k2 = tid; k2 < FC_K; k2 += 256) {
            int p = k2 >> 6, c = k2 & 63;
            dst[k2] = f2bf(row[c*121 + p]);
        }
        return;
    }
    int idx = (blockIdx.x - 64)*256 + tid;
    if (idx < 9216) {  // conv0: [tap][mt][o][ci16]
        int tap = idx >> 10; int r = idx & 1023;
        int mt = r >> 9; int o = (r >> 4) & 31; int ci = r & 15;
        int oc = mt*32 + o;
        float v = (ci < 9) ? conv0_w[(oc*9 + ci)*9 + tap] : 0.f;
        w0[idx] = f2bf(v);
        return;
    }
    idx -= 9216;
    if (idx < 258048) {  // conv1-7: [l][tap][mt][ks][o][kh][e]
        int l = idx / 36864; int r = idx % 36864;
        int tap = r >> 12; int rr = r & 4095;
        int mt = rr >> 11;
        int ks = (rr >> 9) & 3;
        int o  = (rr >> 4) & 31;
        int ci16 = rr & 15;               // kh*8 + e
        int oc = mt*32 + o;
        int ci = ks*16 + ci16;
        wpk[idx] = f2bf(conv_ws[((l*64 + oc)*64 + ci)*9 + tap]);
        return;
    }
    idx -= 258048;
    if (idx < 16384) {  // w_ih^T: [k][g]
        int k = idx >> 8; int g = idx & 255;
        wihT[idx] = w_ih[g*64 + k];
        return;
    }
    idx -= 16384;
    if (idx < 256) bsum[idx] = b_ih[idx] + b_hh[idx];
}

// ========== fused 8-layer conv stack: R22 = R17 + cell-rotated LDS slots ==========
// R22 theory: SQ_LDS_BANK_CONFLICT = 2.225e7 (13% of conv wall, constant all
// session). Cause: each cell's 128B row is bank-ALIGNED (128B = 32 banks x 4B),
// so bank = slot*4+word and slot = (G+p)&7 == (const+n)&7 -> lanes n, n+8,
// n+16.. always alias the same 4-bank group (reads, epilogue writes, copy-out).
// Fix: physical slot = (G + q + ((cell>>3)&7)) & 7 -- cell-dependent rotation.
// Lanes n / n+8 have cells differing ~8-12 -> rotation differs 1-2 -> distinct
// banks. Applied consistently at all 3 touch points; conv0's ISTR staging
// unchanged; halo all-zero so rotation-neutral; clamped tail reads in-bounds.
// Base structure = R17 (best measured): N-split 2 waves/frame, (128,3),
// fenced 1-step-ahead A-prefetch with sched_barrier(0).
__global__ __launch_bounds__(128, 3) void conv_stack(
    const float* __restrict__ x,
    const float* __restrict__ conv0_b,
    const float* __restrict__ conv_bs,
    const short* __restrict__ w0,
    const short* __restrict__ wpk,
    short* __restrict__ acts_out)
{
    __shared__ alignas(16) short act[FSZ];   // 21632 B, shared by 2 waves
    const int tid  = threadIdx.x;
    const int lane = tid & 63;
    const int wv   = tid >> 6;     // wave 0/1: owns nt = wv*2 + {0,1}
    const int n    = lane & 31;    // N col / A row (out-channel) index
    const int kh   = lane >> 5;    // k-half: channels kh*8 .. kh*8+7 of each 16
    char* actb = (char*)act;

    const short8 zero8 = {0,0,0,0,0,0,0,0};
    const floatx16 fz16 = {};

    // zero conv0 staging region (13*13*20 = 3380, pad 3392), split 128 thr
    for (int i = tid*8; i < 3392; i += 1024) *(short8*)(&act[i]) = zero8;
    __syncthreads();

    // stage input frame fp32 -> bf16 ([Y][X][ci] stride 20; x is [ci][y][x])
    {
        const float* xf = x + (size_t)blockIdx.x*(C_IN*POS);
        for (int i = tid; i < C_IN*POS; i += 128) {
            int ci = i / POS;
            int p  = i - ci*POS;
            int yy = p / 11;
            int xx = p - yy*11;
            act[((yy+1)*13 + (xx+1))*ISTR + ci] = f2bf(xf[i]);
        }
    }
    __syncthreads();

    floatx16 acc[2][2];    // [mt][local nt]
    #pragma unroll
    for (int mt=0;mt<2;mt++)
        #pragma unroll
        for (int j=0;j<2;j++) acc[mt][j] = fz16;

    // per-local-nt tap-base cell (clamped); vbase = byte base in swizzled layout
    int cell20[2], cellix[2], vbase[2], wbase[2];
    #pragma unroll
    for (int j = 0; j < 2; ++j) {
        int p = (wv*2 + j)*32 + n;
        int pc = (p <= 120) ? p : 120;
        int yy = pc / 11, xx = pc - yy*11;
        int cell = yy*13 + xx;
        cell20[j] = cell*ISTR;
        cellix[j] = cell;
        vbase[j]  = cell*128;
        wbase[j]  = (cell + 14)*128;    // interior cell (+1,+1)
    }
    const bool tail = (wv == 1) && (n > 24);   // p > 120 on local j==1
    // epilogue write rotation: interior cell = cellix + 14
    const int rw0 = ((cellix[0] + 14) >> 3) & 7;
    const int rw1 = ((cellix[1] + 14) >> 3) & 7;

    // ---- conv0 (K real 9, padded to 16; pad is zero in both A and B) ----
    {
        const short* w0l = w0 + n*16 + kh*8;
        #pragma unroll 1
        for (int dy = 0; dy < 3; ++dy) {
            #pragma unroll 1
            for (int dx = 0; dx < 3; ++dx) {
                const short* wt = w0l + (dy*3+dx)*1024;
                short8 a0 = *(const short8*)(wt);
                short8 a1 = *(const short8*)(wt + 512);
                const int so = (dy*13+dx)*ISTR + kh*8;
                #pragma unroll
                for (int j=0;j<2;j++) {
                    const short* bp = act + cell20[j] + so;
                    S8U t;
                    t.h[0] = *(const short4_t*)(bp);
                    t.h[1] = *(const short4_t*)(bp + 4);
                    acc[0][j] = MFMA32(a0, t.v, acc[0][j]);
                    acc[1][j] = MFMA32(a1, t.v, acc[1][j]);
                }
            }
        }
    }

    // conv0 input dead; zero the full swizzled act buffer (halo must be 0)
    __syncthreads();                      // both waves done reading staging
    for (int i = tid*8; i < FSZ; i += 1024) *(short8*)(&act[i]) = zero8;

    // epilogue: bias+relu+bf16 -> rotated-slot act interior (wave writes its 2 nt)
    auto epilogue = [&](const float* bias) {
        __syncthreads();                  // all reads (or zeroing) complete
        #pragma unroll
        for (int mt=0;mt<2;mt++) {
            #pragma unroll
            for (int q=0;q<4;q++) {
                const int ch0 = mt*32 + q*8 + kh*4;
                const floatx4 bb = *(const floatx4*)(bias + ch0);
                // G = mt*4+q; slot = (G + p + rot(cell)) & 7, p mod 8 = n mod 8
                const int s0 = (((mt*4 + q + n + rw0) & 7) << 4) + kh*8;
                const int s1 = (((mt*4 + q + n + rw1) & 7) << 4) + kh*8;
                #pragma unroll
                for (int j=0;j<2;j++) {
                    if (j == 1 && tail) continue;   // p > 120
                    short4_t sv;
                    sv.x = f2bf(fmaxf(acc[mt][j][q*4+0] + bb.x, 0.f));
                    sv.y = f2bf(fmaxf(acc[mt][j][q*4+1] + bb.y, 0.f));
                    sv.z = f2bf(fmaxf(acc[mt][j][q*4+2] + bb.z, 0.f));
                    sv.w = f2bf(fmaxf(acc[mt][j][q*4+3] + bb.w, 0.f));
                    *(short4_t*)(actb + wbase[j] + ((j==0)?s0:s1)) = sv;
                }
            }
        }
        #pragma unroll
        for (int mt=0;mt<2;mt++)
            #pragma unroll
            for (int j=0;j<2;j++) acc[mt][j] = fz16;
        __syncthreads();                  // writes visible before next reads
    };

    epilogue(conv0_b);

    // ---- conv layers 1..7: fenced 1-microstep-ahead A-prefetch + rotated B ----
    {
        short8 AX0,AX1,AX2,AX3, AY0,AY1,AY2,AY3;
        #pragma unroll 1
        for (int l = 1; l < 8; ++l) {
            const short* wl = wpk + (l-1)*36864 + n*16 + kh*8;
            AX0 = *(const short8*)(wl);
            AX1 = *(const short8*)(wl + 2048);
            AX2 = *(const short8*)(wl + 512);
            AX3 = *(const short8*)(wl + 2560);
            #pragma unroll
            for (int i = 0; i < 18; ++i) {
                const int tp = i >> 1, kp = i & 1;
                const int tco = (tp/3)*13 + (tp%3);          // tap cell offset
                const int sb_ = tco*128;
                const int r0 = ((cellix[0] + tco) >> 3) & 7; // per-tap rotation
                const int r1 = ((cellix[1] + tco) >> 3) & 7;
                const int cu_ = (tp/3)*11 + (tp%3) + 4 + kh + n + 4*kp;
                const int so00 = sb_ + (((cu_ + r0) & 7) << 4);
                const int so01 = sb_ + (((cu_ + r1) & 7) << 4);
                const int so10 = sb_ + (((cu_ + r0 + 2) & 7) << 4);
                const int so11 = sb_ + (((cu_ + r1 + 2) & 7) << 4);
                short8 b00 = *(const short8*)(actb + vbase[0] + so00);
                short8 b01 = *(const short8*)(actb + vbase[1] + so01);
                short8 b10 = *(const short8*)(actb + vbase[0] + so10);
                short8 b11 = *(const short8*)(actb + vbase[1] + so11);
                if (i < 17) {
                    const int j = i + 1;
                    const short* wt_ = wl + (j>>1)*4096 + (j&1)*1024;
                    if ((i & 1) == 0) {
                        AY0 = *(const short8*)(wt_);
                        AY1 = *(const short8*)(wt_ + 2048);
                        AY2 = *(const short8*)(wt_ + 512);
                        AY3 = *(const short8*)(wt_ + 2560);
                    } else {
                        AX0 = *(const short8*)(wt_);
                        AX1 = *(const short8*)(wt_ + 2048);
                        AX2 = *(const short8*)(wt_ + 512);
                        AX3 = *(const short8*)(wt_ + 2560);
                    }
                }
                __builtin_amdgcn_sched_barrier(0);   // loads may not sink below
                if ((i & 1) == 0) {                  // consume AX
                    acc[0][0]=MFMA32(AX0,b00,acc[0][0]); acc[1][0]=MFMA32(AX1,b00,acc[1][0]);
                    acc[0][1]=MFMA32(AX0,b01,acc[0][1]); acc[1][1]=MFMA32(AX1,b01,acc[1][1]);
                    acc[0][0]=MFMA32(AX2,b10,acc[0][0]); acc[1][0]=MFMA32(AX3,b10,acc[1][0]);
                    acc[0][1]=MFMA32(AX2,b11,acc[0][1]); acc[1][1]=MFMA32(AX3,b11,acc[1][1]);
                } else {                             // consume AY
                    acc[0][0]=MFMA32(AY0,b00,acc[0][0]); acc[1][0]=MFMA32(AY1,b00,acc[1][0]);
                    acc[0][1]=MFMA32(AY0,b01,acc[0][1]); acc[1][1]=MFMA32(AY1,b01,acc[1][1]);
                    acc[0][0]=MFMA32(AY2,b10,acc[0][0]); acc[1][0]=MFMA32(AY3,b10,acc[1][0]);
                    acc[0][1]=MFMA32(AY2,b11,acc[0][1]); acc[1][1]=MFMA32(AY3,b11,acc[1][1]);
                }
            }
            epilogue(conv_bs + (l-1)*NF);
        }
    }

    // final copy: acts[f][p*64 + c], un-rotated, coalesced 16B global writes
    {
        short* dst = acts_out + (size_t)blockIdx.x*FC_K;
        #pragma unroll 1
        for (int it = 0; it < 8; ++it) {
            int q = it*128 + tid;
            if (q < 968) {                    // 121 pos * 8 ch-groups
                int p = q >> 3, G = q & 7;
                int yy = p / 11, xx = p - yy*11;
                int cell = (yy+1)*13 + (xx+1);
                int slot = (G + p + ((cell >> 3) & 7)) & 7;
                short8 v = *(const short8*)(actb + cell*128 + slot*16);
                *(short8*)(dst + q*8) = v;
            }
        }
    }
}

// ===== fused FC + xg: xg[f][g] = relu(acts[f]@fcp^T + fc_b) @ wihT + bsum =====
// R21 structure: 8-wave K-split, fenced 1-step-ahead A+B prefetch, vectorized xg.
__global__ __launch_bounds__(512) void fc_xg_kernel(
    const short* __restrict__ acts, const short* __restrict__ fcp,
    const float* __restrict__ fc_b, const float* __restrict__ wihT,
    const float* __restrict__ bsum, float* __restrict__ xg)
{
    __shared__ alignas(16) float red[7*64*16];   // 28672 B
    __shared__ alignas(16) float fbuf[16*64];    // 4096 B
    const int tid  = threadIdx.x;
    const int lane = tid & 63;
    const int w    = tid >> 6;       // 0..7: K split across 8 waves
    const int m    = lane & 15;
    const int kg   = lane >> 4;
    const int bm   = blockIdx.x;     // 256 blocks x 16 frames

    const floatx4 fzero = {0.f,0.f,0.f,0.f};
    floatx4 acc[4];
    #pragma unroll
    for (int nt=0;nt<4;nt++) acc[nt] = fzero;

    const short* arow = acts + (size_t)(bm*16 + m)*FC_K + kg*8;
    const short* brow = fcp + (size_t)m*FC_K + kg*8;

    // fenced 1-step-ahead A+B prefetch, X/Y rotation, K-step 8 (242 chunks)
    {
        short8 aX, aY, bX0,bX1,bX2,bX3, bY0,bY1,bY2,bY3;
        int kc = w;
        if (kc < 242) {
            aX  = *(const short8*)(arow + (size_t)kc*32);
            bX0 = *(const short8*)(brow + (size_t)kc*32);
            bX1 = *(const short8*)(brow + (size_t)16*FC_K + (size_t)kc*32);
            bX2 = *(const short8*)(brow + (size_t)32*FC_K + (size_t)kc*32);
            bX3 = *(const short8*)(brow + (size_t)48*FC_K + (size_t)kc*32);
        }
        while (kc < 242) {
            int k2 = kc + 8;
            if (k2 < 242) {
                aY  = *(const short8*)(arow + (size_t)k2*32);
                bY0 = *(const short8*)(brow + (size_t)k2*32);
                bY1 = *(const short8*)(brow + (size_t)16*FC_K + (size_t)k2*32);
                bY2 = *(const short8*)(brow + (size_t)32*FC_K + (size_t)k2*32);
                bY3 = *(const short8*)(brow + (size_t)48*FC_K + (size_t)k2*32);
            }
            __builtin_amdgcn_sched_barrier(0);   // prefetch may not sink below
            acc[0] = MFMA_B16(aX, bX0, acc[0]);
            acc[1] = MFMA_B16(aX, bX1, acc[1]);
            acc[2] = MFMA_B16(aX, bX2, acc[2]);
            acc[3] = MFMA_B16(aX, bX3, acc[3]);
            kc = k2;
            if (kc >= 242) break;
            int k3 = kc + 8;
            if (k3 < 242) {
                aX  = *(const short8*)(arow + (size_t)k3*32);
                bX0 = *(const short8*)(brow + (size_t)k3*32);
                bX1 = *(const short8*)(brow + (size_t)16*FC_K + (size_t)k3*32);
                bX2 = *(const short8*)(brow + (size_t)32*FC_K + (size_t)k3*32);
                bX3 = *(const short8*)(brow + (size_t)48*FC_K + (size_t)k3*32);
            }
            __builtin_amdgcn_sched_barrier(0);
            acc[0] = MFMA_B16(aY, bY0, acc[0]);
            acc[1] = MFMA_B16(aY, bY1, acc[1]);
            acc[2] = MFMA_B16(aY, bY2, acc[2]);
            acc[3] = MFMA_B16(aY, bY3, acc[3]);
            kc = k3;
        }
    }

    if (w > 0) {
        #pragma unroll
        for (int nt=0;nt<4;nt++)
            *(floatx4*)(&red[((w-1)*64 + lane)*16 + nt*4]) = acc[nt];
    }
    __syncthreads();
    if (w == 0) {
        #pragma unroll
        for (int nt=0;nt<4;nt++)
            for (int j=0;j<7;j++)
                acc[nt] += *(const floatx4*)(&red[(j*64 + lane)*16 + nt*4]);
        #pragma unroll
        for (int nt=0;nt<4;nt++) {
            int unit = nt*16 + m;
            float bias = fc_b[unit];
            int fr = kg*4;                    // local frame 0..15
            fbuf[(fr+0)*NF + unit] = fmaxf(acc[nt].x + bias, 0.f);
            fbuf[(fr+1)*NF + unit] = fmaxf(acc[nt].y + bias, 0.f);
            fbuf[(fr+2)*NF + unit] = fmaxf(acc[nt].z + bias, 0.f);
            fbuf[(fr+3)*NF + unit] = fmaxf(acc[nt].w + bias, 0.f);
        }
    }
    __syncthreads();

    // xg phase: 512 threads; thread (g, half) computes 8 frames x 1 gate
    {
        const int g = tid & 255;
        const int half = tid >> 8;         // 0/1: frames [half*8, half*8+8)
        const int fb = half*8;
        float a[8];
        float bs = bsum[g];
        #pragma unroll
        for (int j=0;j<8;j++) a[j] = bs;
        for (int k4=0;k4<16;k4++) {
            float wk0 = wihT[(k4*4+0)*256 + g];
            float wk1 = wihT[(k4*4+1)*256 + g];
            float wk2 = wihT[(k4*4+2)*256 + g];
            float wk3 = wihT[(k4*4+3)*256 + g];
            #pragma unroll
            for (int j=0;j<8;j++) {
                float4 f = *(const float4*)(&fbuf[(fb+j)*64 + k4*4]);
                a[j] += f.x*wk0 + f.y*wk1 + f.z*wk2 + f.w*wk3;
            }
        }
        float* xo = xg + (size_t)(bm*16 + fb)*256 + g;
        #pragma unroll
        for (int j=0;j<8;j++) xo[j*256] = a[j];
    }
}

// ================= LSTM recurrence =================
// 256 threads (one gate per thread) + 4 independent partial accums.
// fast sigmoid/tanh: __expf + hw rcp; saturate correctly at +/-inf
__device__ __forceinline__ float sigmf_(float v){
    return __builtin_amdgcn_rcpf(1.f + __expf(-v));
}
__device__ __forceinline__ float tanhf_(float v){
    return 1.f - 2.f*__builtin_amdgcn_rcpf(__expf(2.f*v) + 1.f);
}

__global__ __launch_bounds__(256) void lstm_kernel(
    const float* __restrict__ xg, const float* __restrict__ whh,
    float* __restrict__ hout)
{
    __shared__ alignas(16) float hbuf[64];
    __shared__ alignas(16) float gbuf[256];
    const int g = threadIdx.x;     // gate 0..255
    const int b = blockIdx.x;

    float4 wv[16];
    #pragma unroll
    for (int k=0;k<16;k++) wv[k] = *(const float4*)(whh + g*64 + k*4);

    float c = 0.f;
    if (g < 64) hbuf[g] = 0.f;
    __syncthreads();

    const float* xr = xg + (size_t)(b*128)*256;
    float nx = xr[g];

    for (int ts=0; ts<128; ++ts) {
        float a0 = nx, a1 = 0.f, a2 = 0.f, a3 = 0.f;
        if (ts + 1 < 128) nx = xr[(ts+1)*256 + g];
        #pragma unroll
        for (int k=0;k<4;k++) {
            float4 h0 = *(const float4*)(&hbuf[k*16]);
            float4 h1 = *(const float4*)(&hbuf[k*16+4]);
            float4 h2 = *(const float4*)(&hbuf[k*16+8]);
            float4 h3 = *(const float4*)(&hbuf[k*16+12]);
            float4 w0 = wv[k*4+0], w1 = wv[k*4+1], w2 = wv[k*4+2], w3 = wv[k*4+3];
            a0 += h0.x*w0.x + h0.y*w0.y + h0.z*w0.z + h0.w*w0.w;
            a1 += h1.x*w1.x + h1.y*w1.y + h1.z*w1.z + h1.w*w1.w;
            a2 += h2.x*w2.x + h2.y*w2.y + h2.z*w2.z + h2.w*w2.w;
            a3 += h3.x*w3.x + h3.y*w3.y + h3.z*w3.z + h3.w*w3.w;
        }
        gbuf[g] = (a0 + a1) + (a2 + a3);
        __syncthreads();
        if (g < 64) {   // gate order i,f,g,o
            float ig = sigmf_(gbuf[g]);
            float fg = sigmf_(gbuf[64+g]);
            float gg = tanhf_(gbuf[128+g]);
            float og = sigmf_(gbuf[192+g]);
            c = fg*c + ig*gg;
            float h = og*tanhf_(c);
            hbuf[g] = h;
            hout[(b*128+ts)*64 + g] = h;
        }
        __syncthreads();
    }
}

// ================= policy/value heads (fp32) =================
__global__ __launch_bounds__(64) void heads_kernel(
    const float* __restrict__ hout,
    const float* __restrict__ p1w, const float* __restrict__ p1b,
    const float* __restrict__ p2w, const float* __restrict__ p2b,
    const float* __restrict__ v1w, const float* __restrict__ v1b,
    const float* __restrict__ v2w, const float* __restrict__ v2b,
    float* __restrict__ out)
{
    __shared__ alignas(16) float hbv[64];
    __shared__ alignas(16) float a1[128];
    __shared__ alignas(16) float a2[128];
    const int lane = threadIdx.x;
    const int f = blockIdx.x;
    hbv[lane] = hout[f*64 + lane];
    __syncthreads();
    #pragma unroll
    for (int uu=0; uu<2; ++uu) {
        const int u = lane + uu*64;
        const float4* wp1 = (const float4*)(p1w + u*64);
        const float4* wv1 = (const float4*)(v1w + u*64);
        float s1a=0.f,s1b=0.f,s1c=0.f,s1d=0.f;
        float s2a=0.f,s2b=0.f,s2c=0.f,s2d=0.f;
        #pragma unroll
        for (int k=0;k<4;k++) {
            float4 h0 = *(const float4*)(&hbv[k*16]);
            float4 h1 = *(const float4*)(&hbv[k*16+4]);
            float4 h2 = *(const float4*)(&hbv[k*16+8]);
            float4 h3 = *(const float4*)(&hbv[k*16+12]);
            float4 w0 = wp1[k*4+0], w1 = wp1[k*4+1], w2 = wp1[k*4+2], w3 = wp1[k*4+3];
            s1a += h0.x*w0.x + h0.y*w0.y + h0.z*w0.z + h0.w*w0.w;
            s1b += h1.x*w1.x + h1.y*w1.y + h1.z*w1.z + h1.w*w1.w;
            s1c += h2.x*w2.x + h2.y*w2.y + h2.z*w2.z + h2.w*w2.w;
            s1d += h3.x*w3.x + h3.y*w3.y + h3.z*w3.z + h3.w*w3.w;
            float4 q0 = wv1[k*4+0], q1 = wv1[k*4+1], q2 = wv1[k*4+2], q3 = wv1[k*4+3];
            s2a += h0.x*q0.x + h0.y*q0.y + h0.z*q0.z + h0.w*q0.w;
            s2b += h1.x*q1.x + h1.y*q1.y + h1.z*q1.z + h1.w*q1.w;
            s2c += h2.x*q2.x + h2.y*q2.y + h2.z*q2.z + h2.w*q2.w;
            s2d += h3.x*q3.x + h3.y*q3.y + h3.z*q3.z + h3.w*q3.w;
        }
        a1[u] = fmaxf(p1b[u] + (s1a+s1b)+(s1c+s1d), 0.f);
        a2[u] = fmaxf(v1b[u] + (s2a+s2b)+(s2c+s2d), 0.f);
    }
    __syncthreads();
    if (lane < 56) {
        const int o = lane >> 3, part = lane & 7;   // o: 0..5 policy, 6 value
        const float* src = (o < 6) ? a1 : a2;
        const float* wr  = (o < 6) ? (p2w + o*128) : v2w;
        float s = 0.f;
        const int j0 = part*16;
        #pragma unroll
        for (int j=0;j<16;j++) s += src[j0+j]*wr[j0+j];
        s += __shfl_xor(s, 1);
        s += __shfl_xor(s, 2);
        s += __shfl_xor(s, 4);
        if (part == 0) {
            if (o < 6) out[f*6 + o] = p2b[o] + s;
            else       out[24576 + f] = v2b[0] + s;
        }
    }
}

extern "C" void kernel_launch(void* const* d_in, const int* in_sizes, int n_in,
                              void* d_out, int out_size, void* d_ws, size_t ws_size,
                              hipStream_t stream) {
    const float* x       = (const float*)d_in[0];
    const float* conv0_w = (const float*)d_in[1];
    const float* conv0_b = (const float*)d_in[2];
    const float* conv_ws = (const float*)d_in[3];
    const float* conv_bs = (const float*)d_in[4];
    const float* fc_w    = (const float*)d_in[5];
    const float* fc_b    = (const float*)d_in[6];
    const float* w_ih    = (const float*)d_in[7];
    const float* w_hh    = (const float*)d_in[8];
    const float* b_ih    = (const float*)d_in[9];
    const float* b_hh    = (const float*)d_in[10];
    const float* p1_w    = (const float*)d_in[11];
    const float* p1_b    = (const float*)d_in[12];
    const float* p2_w    = (const float*)d_in[13];
    const float* p2_b    = (const float*)d_in[14];
    const float* v1_w    = (const float*)d_in[15];
    const float* v1_b    = (const float*)d_in[16];
    const float* v2_w    = (const float*)d_in[17];
    const float* v2_b    = (const float*)d_in[18];
    float* out = (float*)d_out;

    char* ws = (char*)d_ws;
    short* w0    = (short*)(ws + OFF_W0);
    short* wpk   = (short*)(ws + OFF_WP);
    short* fcp   = (short*)(ws + OFF_FCP);
    float* wihT  = (float*)(ws + OFF_WIHT);
    float* bsum  = (float*)(ws + OFF_BSUM);
    short* acts  = (short*)(ws + OFF_ACTS);
    float* xgb   = (float*)(ws + OFF_XG);
    float* hout  = (float*)(ws + OFF_HOUT);

    prep_kernel<<<1173, 256, 0, stream>>>(conv0_w, conv_ws, w_ih, b_ih, b_hh,
                                          fc_w, w0, wpk, wihT, bsum, fcp);
    conv_stack<<<N_FRAMES, 128, 0, stream>>>(x, conv0_b, conv_bs, w0, wpk, acts);
    fc_xg_kernel<<<256, 512, 0, stream>>>(acts, fcp, fc_b, wihT, bsum, xgb);
    lstm_kernel<<<32, 256, 0, stream>>>(xgb, w_hh, hout);
    heads_kernel<<<4096, 64, 0, stream>>>(hout, p1_w, p1_b, p2_w, p2_b,
                                          v1_w, v1_b, v2_w, v2_b, out);
}

// Round 11
// 496.140 us; speedup vs baseline: 1.2503x; 1.2503x over previous
//
#include <hip/hip_runtime.h>
#include <hip/hip_bf16.h>

typedef __attribute__((ext_vector_type(8))) short short8;
typedef __attribute__((ext_vector_type(4))) short short4_t;
typedef __attribute__((ext_vector_type(4))) float floatx4;
typedef __attribute__((ext_vector_type(16))) float floatx16;

#define MFMA_B16(a,b,c) __builtin_amdgcn_mfma_f32_16x16x32_bf16((a),(b),(c),0,0,0)
#define MFMA32(a,b,c)   __builtin_amdgcn_mfma_f32_32x32x16_bf16((a),(b),(c),0,0,0)

__device__ __forceinline__ short f2bf(float f) {
    union { __hip_bfloat16 h; short s; } u;
    u.h = __float2bfloat16(f);
    return u.s;
}

union S8U { short4_t h[2]; short8 v; };

// ---------------- problem constants ----------------
#define N_FRAMES 4096
#define C_IN     9
#define POS      121
#define NF       64
#define FC_K     7744     // k = p*64 + c
#define ISTR     20       // conv0 input LDS stride (elems)
#define CSTR     144      // act cell row stride BYTES (R23: 128->144, bank rotation)
#define FSZE     12168    // 169*72 shorts (169 cells x 144 B)

// ---------------- workspace offsets (bytes) ----------------
#define OFF_W0    0                       // [9][2][32][16] bf16 (18432 B)
#define OFF_WP    18432                   // [7][9][2][4][32][2][8] bf16 (516096 B)
#define OFF_FCP   534528                  // [64][7744] bf16, k=p*64+c (991232 B)
#define OFF_WIHT  1525760                 // [64][256] f32 (65536 B)
#define OFF_BSUM  1591296                 // [256] f32 (1024 B)
#define OFF_ACTS  1592320                 // [4096][7744] bf16 (63438848 B)
#define OFF_XG    66079744                // [4096][256] f32 (4194304 B)
#define OFF_HOUT  70274048                // [4096][64] f32 (1048576 B)  end=71322624

// ============ fused prep: conv weights + w_ih^T + biases + fc transpose ============
__global__ __launch_bounds__(256) void prep_kernel(
    const float* __restrict__ conv0_w, const float* __restrict__ conv_ws,
    const float* __restrict__ w_ih,
    const float* __restrict__ b_ih, const float* __restrict__ b_hh,
    const float* __restrict__ fc_w,
    short* __restrict__ w0, short* __restrict__ wpk,
    float* __restrict__ wihT, float* __restrict__ bsum,
    short* __restrict__ fcp)
{
    __shared__ float row[FC_K];          // 30976 B (used by fc-transpose blocks)
    const int tid = threadIdx.x;
    if (blockIdx.x < 64) {               // fc weight transpose: [u][c*121+p] -> [u][p*64+c]
        const int u = blockIdx.x;
        const float* src = fc_w + (size_t)u*FC_K;
        for (int i = tid; i < FC_K; i += 256) row[i] = src[i];
        __syncthreads();
        short* dst = fcp + (size_t)u*FC_K;
        for (int k2 = tid; k2 < FC_K; k2 += 256) {
            int p = k2 >> 6, c = k2 & 63;
            dst[k2] = f2bf(row[c*121 + p]);
        }
        return;
    }
    int idx = (blockIdx.x - 64)*256 + tid;
    if (idx < 9216) {  // conv0: [tap][mt][o][ci16]
        int tap = idx >> 10; int r = idx & 1023;
        int mt = r >> 9; int o = (r >> 4) & 31; int ci = r & 15;
        int oc = mt*32 + o;
        float v = (ci < 9) ? conv0_w[(oc*9 + ci)*9 + tap] : 0.f;
        w0[idx] = f2bf(v);
        return;
    }
    idx -= 9216;
    if (idx < 258048) {  // conv1-7: [l][tap][mt][ks][o][kh][e]
        int l = idx / 36864; int r = idx % 36864;
        int tap = r >> 12; int rr = r & 4095;
        int mt = rr >> 11;
        int ks = (rr >> 9) & 3;
        int o  = (rr >> 4) & 31;
        int ci16 = rr & 15;               // kh*8 + e
        int oc = mt*32 + o;
        int ci = ks*16 + ci16;
        wpk[idx] = f2bf(conv_ws[((l*64 + oc)*64 + ci)*9 + tap]);
        return;
    }
    idx -= 258048;
    if (idx < 16384) {  // w_ih^T: [k][g]
        int k = idx >> 8; int g = idx & 255;
        wihT[idx] = w_ih[g*64 + k];
        return;
    }
    idx -= 16384;
    if (idx < 256) bsum[idx] = b_ih[idx] + b_hh[idx];
}

// ========== fused 8-layer conv stack: R23 = R17 + 144B cell stride ==========
// R22 post-mortem: per-tap slot rotation doubled live address values ->
// spill (FETCH 11->196 GBKB, WRITE 62->158 MBKB, conv 408us). R23 gets the
// SAME cell-dependent bank rotation for free via the ROW STRIDE: 128B rows
// are bank-aligned (bank = slot group, lanes n/n+8/n+16/n+24 alias 4-way);
// 144B rows give row-start bank offset (cell&7)*16B. Checked alias sets:
// cells {0,8,18,28}->rot{0,0,2,4}, {36,46,56,66}->{4,6,0,2} etc -- 4-way
// drops to mostly-0 / worst 2-way (2-way is free, m136). Zero extra
// registers: sb_=tco*144 compile-time, vbase/wbase setup-only. All slot
// math, nt-uniformity, conv0 staging unchanged from R17 (best measured).
// LDS 24336 B/block; 3 blocks/CU = 73.7KB <= 160KB.
__global__ __launch_bounds__(128, 3) void conv_stack(
    const float* __restrict__ x,
    const float* __restrict__ conv0_b,
    const float* __restrict__ conv_bs,
    const short* __restrict__ w0,
    const short* __restrict__ wpk,
    short* __restrict__ acts_out)
{
    __shared__ alignas(16) short act[FSZE];  // 24336 B, shared by 2 waves
    const int tid  = threadIdx.x;
    const int lane = tid & 63;
    const int wv   = tid >> 6;     // wave 0/1: owns nt = wv*2 + {0,1}
    const int n    = lane & 31;    // N col / A row (out-channel) index
    const int kh   = lane >> 5;    // k-half: channels kh*8 .. kh*8+7 of each 16
    char* actb = (char*)act;

    const short8 zero8 = {0,0,0,0,0,0,0,0};
    const floatx16 fz16 = {};

    // zero conv0 staging region (13*13*20 = 3380, pad 3392), split 128 thr
    for (int i = tid*8; i < 3392; i += 1024) *(short8*)(&act[i]) = zero8;
    __syncthreads();

    // stage input frame fp32 -> bf16 ([Y][X][ci] stride 20; x is [ci][y][x])
    {
        const float* xf = x + (size_t)blockIdx.x*(C_IN*POS);
        for (int i = tid; i < C_IN*POS; i += 128) {
            int ci = i / POS;
            int p  = i - ci*POS;
            int yy = p / 11;
            int xx = p - yy*11;
            act[((yy+1)*13 + (xx+1))*ISTR + ci] = f2bf(xf[i]);
        }
    }
    __syncthreads();

    floatx16 acc[2][2];    // [mt][local nt]
    #pragma unroll
    for (int mt=0;mt<2;mt++)
        #pragma unroll
        for (int j=0;j<2;j++) acc[mt][j] = fz16;

    // per-local-nt tap-base cell (clamped); vbase = byte base (144B stride)
    int cell20[2], vbase[2], wbase[2];
    #pragma unroll
    for (int j = 0; j < 2; ++j) {
        int p = (wv*2 + j)*32 + n;
        int pc = (p <= 120) ? p : 120;
        int yy = pc / 11, xx = pc - yy*11;
        int cell = yy*13 + xx;
        cell20[j] = cell*ISTR;
        vbase[j]  = cell*CSTR;
        wbase[j]  = (cell + 14)*CSTR;   // interior cell (+1,+1)
    }
    const bool tail = (wv == 1) && (n > 24);   // p > 120 on local j==1

    // ---- conv0 (K real 9, padded to 16; pad is zero in both A and B) ----
    {
        const short* w0l = w0 + n*16 + kh*8;
        #pragma unroll 1
        for (int dy = 0; dy < 3; ++dy) {
            #pragma unroll 1
            for (int dx = 0; dx < 3; ++dx) {
                const short* wt = w0l + (dy*3+dx)*1024;
                short8 a0 = *(const short8*)(wt);
                short8 a1 = *(const short8*)(wt + 512);
                const int so = (dy*13+dx)*ISTR + kh*8;
                #pragma unroll
                for (int j=0;j<2;j++) {
                    const short* bp = act + cell20[j] + so;
                    S8U t;
                    t.h[0] = *(const short4_t*)(bp);
                    t.h[1] = *(const short4_t*)(bp + 4);
                    acc[0][j] = MFMA32(a0, t.v, acc[0][j]);
                    acc[1][j] = MFMA32(a1, t.v, acc[1][j]);
                }
            }
        }
    }

    // conv0 input dead; zero the full act buffer (halo must be 0)
    __syncthreads();                      // both waves done reading staging
    for (int i = tid*8; i < FSZE; i += 1024) *(short8*)(&act[i]) = zero8;

    // epilogue: bias+relu+bf16 -> act interior (wave writes its 2 nt)
    // C/D layout 32x32 (HW-verified): col = lane&31 = position,
    // row = (r&3) + 8*(r>>2) + 4*kh
    auto epilogue = [&](const float* bias) {
        __syncthreads();                  // all reads (or zeroing) complete
        #pragma unroll
        for (int mt=0;mt<2;mt++) {
            #pragma unroll
            for (int q=0;q<4;q++) {
                const int ch0 = mt*32 + q*8 + kh*4;
                const floatx4 bb = *(const floatx4*)(bias + ch0);
                // G = mt*4+q; slot = (G+p)&7, p mod 8 = n mod 8 -> uniform in nt
                const int soff = (((mt*4 + q + n) & 7) << 4) + kh*8;
                #pragma unroll
                for (int j=0;j<2;j++) {
                    if (j == 1 && tail) continue;   // p > 120
                    short4_t sv;
                    sv.x = f2bf(fmaxf(acc[mt][j][q*4+0] + bb.x, 0.f));
                    sv.y = f2bf(fmaxf(acc[mt][j][q*4+1] + bb.y, 0.f));
                    sv.z = f2bf(fmaxf(acc[mt][j][q*4+2] + bb.z, 0.f));
                    sv.w = f2bf(fmaxf(acc[mt][j][q*4+3] + bb.w, 0.f));
                    *(short4_t*)(actb + wbase[j] + soff) = sv;
                }
            }
        }
        #pragma unroll
        for (int mt=0;mt<2;mt++)
            #pragma unroll
            for (int j=0;j<2;j++) acc[mt][j] = fz16;
        __syncthreads();                  // writes visible before next reads
    };

    epilogue(conv0_b);

    // ---- conv layers 1..7: fenced 1-microstep-ahead A-prefetch (R17) ----
    // micro-step i (0..17): tap tp=i>>1, k-pair kp=i&1 (ks = 2kp, 2kp+1)
    {
        short8 AX0,AX1,AX2,AX3, AY0,AY1,AY2,AY3;
        #pragma unroll 1
        for (int l = 1; l < 8; ++l) {
            const short* wl = wpk + (l-1)*36864 + n*16 + kh*8;
            AX0 = *(const short8*)(wl);
            AX1 = *(const short8*)(wl + 2048);
            AX2 = *(const short8*)(wl + 512);
            AX3 = *(const short8*)(wl + 2560);
            #pragma unroll
            for (int i = 0; i < 18; ++i) {
                const int tp = i >> 1, kp = i & 1;
                const int sb_ = ((tp/3)*13 + (tp%3))*CSTR;   // tap cell byte shift
                const int cu_ = (tp/3)*11 + (tp%3) + 4 + kh + n + 4*kp;
                const int so0 = sb_ + ((cu_ & 7) << 4);
                const int so1 = sb_ + (((cu_ + 2) & 7) << 4);
                short8 b00 = *(const short8*)(actb + vbase[0] + so0);
                short8 b01 = *(const short8*)(actb + vbase[1] + so0);
                short8 b10 = *(const short8*)(actb + vbase[0] + so1);
                short8 b11 = *(const short8*)(actb + vbase[1] + so1);
                if (i < 17) {
                    const int j = i + 1;
                    const short* wt_ = wl + (j>>1)*4096 + (j&1)*1024;
                    if ((i & 1) == 0) {
                        AY0 = *(const short8*)(wt_);
                        AY1 = *(const short8*)(wt_ + 2048);
                        AY2 = *(const short8*)(wt_ + 512);
                        AY3 = *(const short8*)(wt_ + 2560);
                    } else {
                        AX0 = *(const short8*)(wt_);
                        AX1 = *(const short8*)(wt_ + 2048);
                        AX2 = *(const short8*)(wt_ + 512);
                        AX3 = *(const short8*)(wt_ + 2560);
                    }
                }
                __builtin_amdgcn_sched_barrier(0);   // loads may not sink below
                if ((i & 1) == 0) {                  // consume AX
                    acc[0][0]=MFMA32(AX0,b00,acc[0][0]); acc[1][0]=MFMA32(AX1,b00,acc[1][0]);
                    acc[0][1]=MFMA32(AX0,b01,acc[0][1]); acc[1][1]=MFMA32(AX1,b01,acc[1][1]);
                    acc[0][0]=MFMA32(AX2,b10,acc[0][0]); acc[1][0]=MFMA32(AX3,b10,acc[1][0]);
                    acc[0][1]=MFMA32(AX2,b11,acc[0][1]); acc[1][1]=MFMA32(AX3,b11,acc[1][1]);
                } else {                             // consume AY
                    acc[0][0]=MFMA32(AY0,b00,acc[0][0]); acc[1][0]=MFMA32(AY1,b00,acc[1][0]);
                    acc[0][1]=MFMA32(AY0,b01,acc[0][1]); acc[1][1]=MFMA32(AY1,b01,acc[1][1]);
                    acc[0][0]=MFMA32(AY2,b10,acc[0][0]); acc[1][0]=MFMA32(AY3,b10,acc[1][0]);
                    acc[0][1]=MFMA32(AY2,b11,acc[0][1]); acc[1][1]=MFMA32(AY3,b11,acc[1][1]);
                }
            }
            epilogue(conv_bs + (l-1)*NF);
        }
    }

    // final copy: acts[f][p*64 + c], coalesced 16B global writes
    {
        short* dst = acts_out + (size_t)blockIdx.x*FC_K;
        #pragma unroll 1
        for (int it = 0; it < 8; ++it) {
            int q = it*128 + tid;
            if (q < 968) {                    // 121 pos * 8 ch-groups
                int p = q >> 3, G = q & 7;
                int yy = p / 11, xx = p - yy*11;
                int cell = (yy+1)*13 + (xx+1);
                int slot = (G + p) & 7;
                short8 v = *(const short8*)(actb + cell*CSTR + slot*16);
                *(short8*)(dst + q*8) = v;
            }
        }
    }
}

// ===== fused FC + xg: xg[f][g] = relu(acts[f]@fcp^T + fc_b) @ wihT + bsum =====
// R21 structure: 8-wave K-split, fenced 1-step-ahead A+B prefetch, vectorized xg.
__global__ __launch_bounds__(512) void fc_xg_kernel(
    const short* __restrict__ acts, const short* __restrict__ fcp,
    const float* __restrict__ fc_b, const float* __restrict__ wihT,
    const float* __restrict__ bsum, float* __restrict__ xg)
{
    __shared__ alignas(16) float red[7*64*16];   // 28672 B
    __shared__ alignas(16) float fbuf[16*64];    // 4096 B
    const int tid  = threadIdx.x;
    const int lane = tid & 63;
    const int w    = tid >> 6;       // 0..7: K split across 8 waves
    const int m    = lane & 15;
    const int kg   = lane >> 4;
    const int bm   = blockIdx.x;     // 256 blocks x 16 frames

    const floatx4 fzero = {0.f,0.f,0.f,0.f};
    floatx4 acc[4];
    #pragma unroll
    for (int nt=0;nt<4;nt++) acc[nt] = fzero;

    const short* arow = acts + (size_t)(bm*16 + m)*FC_K + kg*8;
    const short* brow = fcp + (size_t)m*FC_K + kg*8;

    // fenced 1-step-ahead A+B prefetch, X/Y rotation, K-step 8 (242 chunks)
    {
        short8 aX, aY, bX0,bX1,bX2,bX3, bY0,bY1,bY2,bY3;
        int kc = w;
        if (kc < 242) {
            aX  = *(const short8*)(arow + (size_t)kc*32);
            bX0 = *(const short8*)(brow + (size_t)kc*32);
            bX1 = *(const short8*)(brow + (size_t)16*FC_K + (size_t)kc*32);
            bX2 = *(const short8*)(brow + (size_t)32*FC_K + (size_t)kc*32);
            bX3 = *(const short8*)(brow + (size_t)48*FC_K + (size_t)kc*32);
        }
        while (kc < 242) {
            int k2 = kc + 8;
            if (k2 < 242) {
                aY  = *(const short8*)(arow + (size_t)k2*32);
                bY0 = *(const short8*)(brow + (size_t)k2*32);
                bY1 = *(const short8*)(brow + (size_t)16*FC_K + (size_t)k2*32);
                bY2 = *(const short8*)(brow + (size_t)32*FC_K + (size_t)k2*32);
                bY3 = *(const short8*)(brow + (size_t)48*FC_K + (size_t)k2*32);
            }
            __builtin_amdgcn_sched_barrier(0);   // prefetch may not sink below
            acc[0] = MFMA_B16(aX, bX0, acc[0]);
            acc[1] = MFMA_B16(aX, bX1, acc[1]);
            acc[2] = MFMA_B16(aX, bX2, acc[2]);
            acc[3] = MFMA_B16(aX, bX3, acc[3]);
            kc = k2;
            if (kc >= 242) break;
            int k3 = kc + 8;
            if (k3 < 242) {
                aX  = *(const short8*)(arow + (size_t)k3*32);
                bX0 = *(const short8*)(brow + (size_t)k3*32);
                bX1 = *(const short8*)(brow + (size_t)16*FC_K + (size_t)k3*32);
                bX2 = *(const short8*)(brow + (size_t)32*FC_K + (size_t)k3*32);
                bX3 = *(const short8*)(brow + (size_t)48*FC_K + (size_t)k3*32);
            }
            __builtin_amdgcn_sched_barrier(0);
            acc[0] = MFMA_B16(aY, bY0, acc[0]);
            acc[1] = MFMA_B16(aY, bY1, acc[1]);
            acc[2] = MFMA_B16(aY, bY2, acc[2]);
            acc[3] = MFMA_B16(aY, bY3, acc[3]);
            kc = k3;
        }
    }

    if (w > 0) {
        #pragma unroll
        for (int nt=0;nt<4;nt++)
            *(floatx4*)(&red[((w-1)*64 + lane)*16 + nt*4]) = acc[nt];
    }
    __syncthreads();
    if (w == 0) {
        #pragma unroll
        for (int nt=0;nt<4;nt++)
            for (int j=0;j<7;j++)
                acc[nt] += *(const floatx4*)(&red[(j*64 + lane)*16 + nt*4]);
        #pragma unroll
        for (int nt=0;nt<4;nt++) {
            int unit = nt*16 + m;
            float bias = fc_b[unit];
            int fr = kg*4;                    // local frame 0..15
            fbuf[(fr+0)*NF + unit] = fmaxf(acc[nt].x + bias, 0.f);
            fbuf[(fr+1)*NF + unit] = fmaxf(acc[nt].y + bias, 0.f);
            fbuf[(fr+2)*NF + unit] = fmaxf(acc[nt].z + bias, 0.f);
            fbuf[(fr+3)*NF + unit] = fmaxf(acc[nt].w + bias, 0.f);
        }
    }
    __syncthreads();

    // xg phase: 512 threads; thread (g, half) computes 8 frames x 1 gate
    {
        const int g = tid & 255;
        const int half = tid >> 8;         // 0/1: frames [half*8, half*8+8)
        const int fb = half*8;
        float a[8];
        float bs = bsum[g];
        #pragma unroll
        for (int j=0;j<8;j++) a[j] = bs;
        for (int k4=0;k4<16;k4++) {
            float wk0 = wihT[(k4*4+0)*256 + g];
            float wk1 = wihT[(k4*4+1)*256 + g];
            float wk2 = wihT[(k4*4+2)*256 + g];
            float wk3 = wihT[(k4*4+3)*256 + g];
            #pragma unroll
            for (int j=0;j<8;j++) {
                float4 f = *(const float4*)(&fbuf[(fb+j)*64 + k4*4]);
                a[j] += f.x*wk0 + f.y*wk1 + f.z*wk2 + f.w*wk3;
            }
        }
        float* xo = xg + (size_t)(bm*16 + fb)*256 + g;
        #pragma unroll
        for (int j=0;j<8;j++) xo[j*256] = a[j];
    }
}

// ================= LSTM recurrence =================
// 256 threads (one gate per thread) + 4 independent partial accums.
// fast sigmoid/tanh: __expf + hw rcp; saturate correctly at +/-inf
__device__ __forceinline__ float sigmf_(float v){
    return __builtin_amdgcn_rcpf(1.f + __expf(-v));
}
__device__ __forceinline__ float tanhf_(float v){
    return 1.f - 2.f*__builtin_amdgcn_rcpf(__expf(2.f*v) + 1.f);
}

__global__ __launch_bounds__(256) void lstm_kernel(
    const float* __restrict__ xg, const float* __restrict__ whh,
    float* __restrict__ hout)
{
    __shared__ alignas(16) float hbuf[64];
    __shared__ alignas(16) float gbuf[256];
    const int g = threadIdx.x;     // gate 0..255
    const int b = blockIdx.x;

    float4 wv[16];
    #pragma unroll
    for (int k=0;k<16;k++) wv[k] = *(const float4*)(whh + g*64 + k*4);

    float c = 0.f;
    if (g < 64) hbuf[g] = 0.f;
    __syncthreads();

    const float* xr = xg + (size_t)(b*128)*256;
    float nx = xr[g];

    for (int ts=0; ts<128; ++ts) {
        float a0 = nx, a1 = 0.f, a2 = 0.f, a3 = 0.f;
        if (ts + 1 < 128) nx = xr[(ts+1)*256 + g];
        #pragma unroll
        for (int k=0;k<4;k++) {
            float4 h0 = *(const float4*)(&hbuf[k*16]);
            float4 h1 = *(const float4*)(&hbuf[k*16+4]);
            float4 h2 = *(const float4*)(&hbuf[k*16+8]);
            float4 h3 = *(const float4*)(&hbuf[k*16+12]);
            float4 w0 = wv[k*4+0], w1 = wv[k*4+1], w2 = wv[k*4+2], w3 = wv[k*4+3];
            a0 += h0.x*w0.x + h0.y*w0.y + h0.z*w0.z + h0.w*w0.w;
            a1 += h1.x*w1.x + h1.y*w1.y + h1.z*w1.z + h1.w*w1.w;
            a2 += h2.x*w2.x + h2.y*w2.y + h2.z*w2.z + h2.w*w2.w;
            a3 += h3.x*w3.x + h3.y*w3.y + h3.z*w3.z + h3.w*w3.w;
        }
        gbuf[g] = (a0 + a1) + (a2 + a3);
        __syncthreads();
        if (g < 64) {   // gate order i,f,g,o
            float ig = sigmf_(gbuf[g]);
            float fg = sigmf_(gbuf[64+g]);
            float gg = tanhf_(gbuf[128+g]);
            float og = sigmf_(gbuf[192+g]);
            c = fg*c + ig*gg;
            float h = og*tanhf_(c);
            hbuf[g] = h;
            hout[(b*128+ts)*64 + g] = h;
        }
        __syncthreads();
    }
}

// ================= policy/value heads (fp32) =================
__global__ __launch_bounds__(64) void heads_kernel(
    const float* __restrict__ hout,
    const float* __restrict__ p1w, const float* __restrict__ p1b,
    const float* __restrict__ p2w, const float* __restrict__ p2b,
    const float* __restrict__ v1w, const float* __restrict__ v1b,
    const float* __restrict__ v2w, const float* __restrict__ v2b,
    float* __restrict__ out)
{
    __shared__ alignas(16) float hbv[64];
    __shared__ alignas(16) float a1[128];
    __shared__ alignas(16) float a2[128];
    const int lane = threadIdx.x;
    const int f = blockIdx.x;
    hbv[lane] = hout[f*64 + lane];
    __syncthreads();
    #pragma unroll
    for (int uu=0; uu<2; ++uu) {
        const int u = lane + uu*64;
        const float4* wp1 = (const float4*)(p1w + u*64);
        const float4* wv1 = (const float4*)(v1w + u*64);
        float s1a=0.f,s1b=0.f,s1c=0.f,s1d=0.f;
        float s2a=0.f,s2b=0.f,s2c=0.f,s2d=0.f;
        #pragma unroll
        for (int k=0;k<4;k++) {
            float4 h0 = *(const float4*)(&hbv[k*16]);
            float4 h1 = *(const float4*)(&hbv[k*16+4]);
            float4 h2 = *(const float4*)(&hbv[k*16+8]);
            float4 h3 = *(const float4*)(&hbv[k*16+12]);
            float4 w0 = wp1[k*4+0], w1 = wp1[k*4+1], w2 = wp1[k*4+2], w3 = wp1[k*4+3];
            s1a += h0.x*w0.x + h0.y*w0.y + h0.z*w0.z + h0.w*w0.w;
            s1b += h1.x*w1.x + h1.y*w1.y + h1.z*w1.z + h1.w*w1.w;
            s1c += h2.x*w2.x + h2.y*w2.y + h2.z*w2.z + h2.w*w2.w;
            s1d += h3.x*w3.x + h3.y*w3.y + h3.z*w3.z + h3.w*w3.w;
            float4 q0 = wv1[k*4+0], q1 = wv1[k*4+1], q2 = wv1[k*4+2], q3 = wv1[k*4+3];
            s2a += h0.x*q0.x + h0.y*q0.y + h0.z*q0.z + h0.w*q0.w;
            s2b += h1.x*q1.x + h1.y*q1.y + h1.z*q1.z + h1.w*q1.w;
            s2c += h2.x*q2.x + h2.y*q2.y + h2.z*q2.z + h2.w*q2.w;
            s2d += h3.x*q3.x + h3.y*q3.y + h3.z*q3.z + h3.w*q3.w;
        }
        a1[u] = fmaxf(p1b[u] + (s1a+s1b)+(s1c+s1d), 0.f);
        a2[u] = fmaxf(v1b[u] + (s2a+s2b)+(s2c+s2d), 0.f);
    }
    __syncthreads();
    if (lane < 56) {
        const int o = lane >> 3, part = lane & 7;   // o: 0..5 policy, 6 value
        const float* src = (o < 6) ? a1 : a2;
        const float* wr  = (o < 6) ? (p2w + o*128) : v2w;
        float s = 0.f;
        const int j0 = part*16;
        #pragma unroll
        for (int j=0;j<16;j++) s += src[j0+j]*wr[j0+j];
        s += __shfl_xor(s, 1);
        s += __shfl_xor(s, 2);
        s += __shfl_xor(s, 4);
        if (part == 0) {
            if (o < 6) out[f*6 + o] = p2b[o] + s;
            else       out[24576 + f] = v2b[0] + s;
        }
    }
}

extern "C" void kernel_launch(void* const* d_in, const int* in_sizes, int n_in,
                              void* d_out, int out_size, void* d_ws, size_t ws_size,
                              hipStream_t stream) {
    const float* x       = (const float*)d_in[0];
    const float* conv0_w = (const float*)d_in[1];
    const float* conv0_b = (const float*)d_in[2];
    const float* conv_ws = (const float*)d_in[3];
    const float* conv_bs = (const float*)d_in[4];
    const float* fc_w    = (const float*)d_in[5];
    const float* fc_b    = (const float*)d_in[6];
    const float* w_ih    = (const float*)d_in[7];
    const float* w_hh    = (const float*)d_in[8];
    const float* b_ih    = (const float*)d_in[9];
    const float* b_hh    = (const float*)d_in[10];
    const float* p1_w    = (const float*)d_in[11];
    const float* p1_b    = (const float*)d_in[12];
    const float* p2_w    = (const float*)d_in[13];
    const float* p2_b    = (const float*)d_in[14];
    const float* v1_w    = (const float*)d_in[15];
    const float* v1_b    = (const float*)d_in[16];
    const float* v2_w    = (const float*)d_in[17];
    const float* v2_b    = (const float*)d_in[18];
    float* out = (float*)d_out;

    char* ws = (char*)d_ws;
    short* w0    = (short*)(ws + OFF_W0);
    short* wpk   = (short*)(ws + OFF_WP);
    short* fcp   = (short*)(ws + OFF_FCP);
    float* wihT  = (float*)(ws + OFF_WIHT);
    float* bsum  = (float*)(ws + OFF_BSUM);
    short* acts  = (short*)(ws + OFF_ACTS);
    float* xgb   = (float*)(ws + OFF_XG);
    float* hout  = (float*)(ws + OFF_HOUT);

    prep_kernel<<<1173, 256, 0, stream>>>(conv0_w, conv_ws, w_ih, b_ih, b_hh,
                                          fc_w, w0, wpk, wihT, bsum, fcp);
    conv_stack<<<N_FRAMES, 128, 0, stream>>>(x, conv0_b, conv_bs, w0, wpk, acts);
    fc_xg_kernel<<<256, 512, 0, stream>>>(acts, fcp, fc_b, wihT, bsum, xgb);
    lstm_kernel<<<32, 256, 0, stream>>>(xgb, w_hh, hout);
    heads_kernel<<<4096, 64, 0, stream>>>(hout, p1_w, p1_b, p2_w, p2_b,
                                          v1_w, v1_b, v2_w, v2_b, out);
}